// Round 3
// baseline (406.343 us; speedup 1.0000x reference)
//
#include <hip/hip_runtime.h>

// LSTMTrafficPredictor: fused 2-layer LSTM + FC head via MFMA.
// B=2048, T=512, IN=4, H1=64, H2=32, FC=16, OUT=1.
//
// R20: critical-path surgery on the latency-bound R19 kernel.
// R19 post-mortem: removed ~130cy/SIMD/step of VALU issue (VALUBusy 50->42)
// yet time was FLAT (357->356us) -> step is pinned by the serial chain:
// barrier -> z ds_read -> 3-deep MFMA -> gsc LDS write->read round-trip ->
// ACT1 trans chain -> h1 store -> barrier. ~40% of cycles nothing can issue.
// R20 changes (all latency-path cuts):
//  (a) ds_swizzle redistribution: ACT1's gate spread is exactly "lane L takes
//      lane L^8's a1_1" -> 4x ds_swizzle_b32(xor 8) + 4 cndmask replaces the
//      gsc write(2xb128)+read(b128) round-trip (one LDS pass, no store->load
//      serialization). ACT2 (reg-only) still hides the swizzle latency.
//  (b) x folded into MFMA C-init: cx = bias + Wih1*x(s) computed on VALU one
//      step AHEAD (off-chain, 32 fma/wave/step in idle slots). Deletes z2
//      ds_read, 2 of 9 MFMAs, the x LDS staging path; L1 MFMA chain 3->2.
//  (c) L2 chain split: z3 term as parallel MFMA with C=0 + f4 add -> MFMA
//      dep depth 2 everywhere.
// CLOSED AXES (measured): issue-trimming (R19 flat - latency-bound), 
// multi-block/CU (spill + grid=256=CU count), MB=16 (half CUs idle),
// cross-wave ACT2 redistribution (2nd barrier, R16 regressed).
// Structure: MB=8, BLK=512, grid=256, bounds(512,2), AGPR-pinned frags,
// unroll-2 ping-pong, 1 barrier/step, exp2-folded weights (R19).
// k-map (K=128): [h1(0..63) | x-unused(64..95) | h2(96..127)]
//   L1: 2 tiles/wave (unit w*8+nt*4+quad, acc[rg]=gate rg), ks {0,1}
//   L2: 1 tile/wave  (unit w*4+quad,      acc[rg]=gate rg), ks {0,1,3}
//   z offset(k,n) = (k>>5)*512 + (((k>>3)&3)*16+n)*8 + (k&7); frag read = lane*8.
// ACT1 job map: lane (quad,col) -> unit w*8 + (col>>3)*4 + quad, batch col&7;
//   col<8 lanes use own a1_0, col>=8 lanes use swizzled(xor8) a1_1.

#define T_LEN 512
#define IN_F  4
#define H1    64
#define H2    32
#define FCN   16
#define MB    8
#define BLK   512

typedef __attribute__((ext_vector_type(8))) short s8b;  // 8 bf16 = 4 VGPR
typedef __attribute__((ext_vector_type(4))) float f4;   // MFMA acc
typedef __attribute__((ext_vector_type(4))) int   i4;   // 4 dwords (pin unit)

union S8U { s8b v; i4 d; unsigned short u[8]; };
union F4U { f4 v; i4 d; float f[4]; };

// Pin 4 consecutive regs into AGPRs; asm def kills rematerialization.
#define APIN4(x) asm volatile("" : "+a"((x).d))

#define MF(a, b, c) __builtin_amdgcn_mfma_f32_16x16x32_bf16((a), (b), (c), 0, 0, 0)
#define EX2(x) __builtin_amdgcn_exp2f(x)

#define L2E   1.4426950408889634f
#define L2E2  2.885390081777927f   // 2*log2(e)

__device__ __forceinline__ float rcp_(float x) { return __builtin_amdgcn_rcpf(x); }
// tanh(x) via exp2: 1 - 2/(2^(2x*log2e)+1)
__device__ __forceinline__ float tanh_(float x) {
    return 1.0f - 2.0f * rcp_(EX2(x * L2E2) + 1.0f);
}

__device__ __forceinline__ unsigned short bf16_rne(float f) {   // loader only
    unsigned u = __float_as_uint(f);
    u = u + 0x7FFFu + ((u >> 16) & 1u);
    return (unsigned short)(u >> 16);
}
__device__ __forceinline__ unsigned short bf16_cvt(float f) {   // hot path: 1 instr
    unsigned r;
    asm("v_cvt_pk_bf16_f32 %0, %1, %2" : "=v"(r) : "v"(f), "v"(f));
    return (unsigned short)r;
}

// ---- step-body macros (P = read buffer, NP = write buffer, compile-time) ----
// 7 MFMA/wave/step; L1 C-init = cx (bias + Wih1*x, computed prev step);
// L2 C-init = pinned bb2; dep depth 2 everywhere (z3 term parallel + add).
#define STEP_MFMA(P, CA, CB)                                                    \
    f4 a1_0, a1_1, ac2;                                                         \
    {                                                                           \
        const s8b z0 = *(const s8b*)(&zz[P][0] + 0 * 512 + offF);               \
        const s8b z1 = *(const s8b*)(&zz[P][0] + 1 * 512 + offF);               \
        const s8b z3 = *(const s8b*)(&zz[P][0] + 3 * 512 + offF);               \
        a1_0 = MF(wf1[0][0].v, z0, CA);                                         \
        a1_1 = MF(wf1[1][0].v, z0, CB);                                         \
        ac2  = MF(wf2[0].v,    z0, bb2.v);                                      \
        const f4 q2 = MF(wf2[2].v, z3, fz);                                     \
        a1_0 = MF(wf1[0][1].v, z1, a1_0);                                       \
        a1_1 = MF(wf1[1][1].v, z1, a1_1);                                       \
        ac2  = MF(wf2[1].v,    z1, ac2);                                        \
        ac2  = ac2 + q2;                                                        \
    }

// In-register ACT1 redistribution: lane L^8's a1_1 -> lane L (col>=8 lanes).
// Single LDS-pipe pass; no write->read serialization, no gsc buffer.
#define STEP_REDIST()                                                           \
    F4U rsw;                                                                    \
    {                                                                           \
        F4U t_; t_.v = a1_1;                                                    \
        rsw.d[0] = __builtin_amdgcn_ds_swizzle(t_.d[0], 0x201F);                \
        rsw.d[1] = __builtin_amdgcn_ds_swizzle(t_.d[1], 0x201F);                \
        rsw.d[2] = __builtin_amdgcn_ds_swizzle(t_.d[2], 0x201F);                \
        rsw.d[3] = __builtin_amdgcn_ds_swizzle(t_.d[3], 0x201F);                \
    }

// Gates pre-scaled: i,f,o rows by log2e; g rows by 2*log2e.
#define STEP_ACT1_FIN(NP)                                                       \
    {                                                                           \
        f4 g_;                                                                  \
        _Pragma("unroll")                                                       \
        for (int j_ = 0; j_ < 4; ++j_)                                          \
            g_[j_] = lowc ? a1_0[j_] : rsw.f[j_];                               \
        const float dI = 1.0f + EX2(-g_[0]);                                    \
        const float dF = 1.0f + EX2(-g_[1]);                                    \
        const float rIF = rcp_(dI * dF);                                        \
        const float I = dF * rIF, F = dI * rIF;                                 \
        const float dG = EX2(g_[2]) + 1.0f;                                     \
        const float dO = 1.0f + EX2(-g_[3]);                                    \
        const float rGO = rcp_(dG * dO);                                        \
        const float Gg = 1.0f - 2.0f * (dO * rGO), O = dG * rGO;                \
        c1 = fmaf(F, c1, I * Gg);                                               \
        zz[NP][offH] = bf16_cvt(O * tanh_(c1));                                 \
    }

#define STEP_ACT2(NP)                                                           \
    {                                                                           \
        const float dI = 1.0f + EX2(-ac2[0]);                                   \
        const float dF = 1.0f + EX2(-ac2[1]);                                   \
        const float rIF = rcp_(dI * dF);                                        \
        const float I = dF * rIF, F = dI * rIF;                                 \
        const float dG = EX2(ac2[2]) + 1.0f;                                    \
        const float dO = 1.0f + EX2(-ac2[3]);                                   \
        const float rGO = rcp_(dG * dO);                                        \
        const float Gg = 1.0f - 2.0f * (dO * rGO), O = dG * rGO;                \
        c2 = fmaf(F, c2, I * Gg);                                               \
        const float h = O * tanh_(c2);                                          \
        if (col < MB) zz[NP][off2] = bf16_cvt(h);                               \
    }

// Next-step L1 C-init: cx = bias + Wih1*x(s+1), all pre-scaled. Off-chain.
#define CX_COMPUTE(CA, CB, XV)                                                  \
    {                                                                           \
        CA = bb1[0].v; CB = bb1[1].v;                                           \
        _Pragma("unroll")                                                       \
        for (int j_ = 0; j_ < 4; ++j_)                                          \
            _Pragma("unroll")                                                   \
            for (int f_ = 0; f_ < IN_F; ++f_) {                                 \
                CA[j_] = fmaf(W1x[0][j_][f_], (XV)[f_], CA[j_]);                \
                CB[j_] = fmaf(W1x[1][j_][f_], (XV)[f_], CB[j_]);                \
            }                                                                   \
    }

__global__ __launch_bounds__(BLK, 2)
void lstm_mfma(const float* __restrict__ x,
               const float* __restrict__ Wih1, const float* __restrict__ Whh1,
               const float* __restrict__ bih1, const float* __restrict__ bhh1,
               const float* __restrict__ Wih2, const float* __restrict__ Whh2,
               const float* __restrict__ bih2, const float* __restrict__ bhh2,
               const float* __restrict__ fc1_w, const float* __restrict__ fc1_b,
               const float* __restrict__ fc2_w, const float* __restrict__ fc2_b,
               float* __restrict__ out)
{
    __shared__ __align__(16) unsigned short zz[2][2048];     // 8 KB
    __shared__ __align__(16) float h2f[MB * H2];
    __shared__ __align__(16) float fcs[MB * FCN];

    const int t    = threadIdx.x;
    const int lane = t & 63;
    const int w    = t >> 6;      // wave 0..7
    const int col  = lane & 15;   // batch col (valid < MB) / A-frag row
    const int quad = lane >> 4;
    const int b0   = blockIdx.x * MB;
    const bool lowc = (col < 8);

    // ---- weight fragments (gate-complete interleaved mapping, bf16) ----
    // exp2-folding: gate rg; g-gate (rg==2) x 2*log2e.
    const float wsc = ((col & 3) == 2) ? L2E2 : L2E;
    S8U wf1[2][2];                // layer1: 2 tiles x ks {0,1} (h1 only)
    S8U wf2[3];                   // layer2: 1 tile  x ks {0,1,3}
    #pragma unroll
    for (int nt = 0; nt < 2; ++nt) {
        const int r1 = (col & 3) * 64 + w * 8 + nt * 4 + (col >> 2);
        #pragma unroll
        for (int ks = 0; ks < 2; ++ks) {
            #pragma unroll
            for (int j = 0; j < 8; ++j) {
                const int k = ks * 32 + quad * 8 + j;       // k < 64 -> Whh1
                wf1[nt][ks].u[j] = bf16_rne(Whh1[r1 * H1 + k] * wsc);
            }
        }
    }
    {
        const int r2 = (col & 3) * 32 + w * 4 + (col >> 2);
        #pragma unroll
        for (int kf = 0; kf < 3; ++kf) {
            #pragma unroll
            for (int j = 0; j < 8; ++j) {
                const int k = ((kf < 2) ? kf * 32 : 96) + quad * 8 + j;
                const float wv = (k < H1) ? Wih2[r2 * H1 + k]
                                          : Whh2[r2 * H2 + (k - 96)];
                wf2[kf].u[j] = bf16_rne(wv * wsc);
            }
        }
    }
    // x-weights (f32, pre-scaled) for the per-step C-init: lane's acc row j
    // of tile nt is W-row j*64 + w*8 + nt*4 + quad.
    float W1x[2][4][4];
    #pragma unroll
    for (int nt = 0; nt < 2; ++nt)
        #pragma unroll
        for (int j = 0; j < 4; ++j) {
            const float gs = (j == 2) ? L2E2 : L2E;
            const int r = j * 64 + w * 8 + nt * 4 + quad;
            #pragma unroll
            for (int f = 0; f < IN_F; ++f)
                W1x[nt][j][f] = Wih1[r * IN_F + f] * gs;
        }

    // biases (pre-scaled): bb1 feeds CX_COMPUTE (VGPR); bb2 is MFMA C-init.
    const int u2 = w * 4 + quad;              // layer2 unit
    F4U bb1[2], bb2;
    #pragma unroll
    for (int j = 0; j < 4; ++j) {
        const float bsc = (j == 2) ? L2E2 : L2E;
        const int u1a = w * 8 + quad;         // nt=0 unit
        const int u1b = w * 8 + 4 + quad;     // nt=1 unit
        bb1[0].f[j] = (bih1[j * 64 + u1a] + bhh1[j * 64 + u1a]) * bsc;
        bb1[1].f[j] = (bih1[j * 64 + u1b] + bhh1[j * 64 + u1b]) * bsc;
        bb2.f[j]    = (bih2[j * 32 + u2]  + bhh2[j * 32 + u2])  * bsc;
    }

    // ---- PIN recurrent fragments + bb2 into AGPRs (32 AGPR) ----
    #pragma unroll
    for (int nt = 0; nt < 2; ++nt)
        #pragma unroll
        for (int ks = 0; ks < 2; ++ks) APIN4(wf1[nt][ks]);
    #pragma unroll
    for (int kf = 0; kf < 3; ++kf) APIN4(wf2[kf]);
    APIN4(bb2);

    const f4 fz = {0.f, 0.f, 0.f, 0.f};

    // ---- init LDS: zero z (both buffers) ----
    {
        int* pz = (int*)zz;       // 2*2048 shorts = 2048 ints
        #pragma unroll
        for (int i = 0; i < 4; ++i) pz[t + i * BLK] = 0;
    }
    float c1 = 0.f;   // ACT1 job: unit uH = w*8+(col>>3)*4+quad, batch col&7
    float c2 = 0.f;   // layer2 unit u2, batch col

    // store offsets
    const int uH   = w * 8 + ((col >> 3) << 2) + quad;
    const int nH   = col & 7;
    const int offH = (uH >> 5) * 512 + (((uH >> 3) & 3) * 16 + nH) * 8 + (uH & 7);
    const int off2 = 1536 + (((u2 >> 3) & 3) * 16 + col) * 8 + (u2 & 7);
    const int offF = lane * 8;                     // frag read base

    // x stream: every lane reads its batch row (col&7) directly from global.
    const float* xq = x + (size_t)(b0 + (col & 7)) * T_LEN * IN_F;
    f4 cxA0, cxA1, cxB0, cxB1;
    {
        const f4 xv0 = *(const f4*)xq;             // x(0)
        CX_COMPUTE(cxA0, cxA1, xv0)
    }
    __syncthreads();

    // ================= main recurrence: unrolled x2, 1 barrier/step ==========
    #pragma unroll 1
    for (int s2 = 0; s2 < T_LEN / 2; ++s2) {
        // ---------- body A: s = 2*s2 (read zz[0], write zz[1]) ----------
        {
            const f4 xvn = *(const f4*)(xq + (2 * s2 + 1) * IN_F);  // x(s+1)
            STEP_MFMA(0, cxA0, cxA1)
            STEP_REDIST()
            if (s2 != 0) STEP_ACT2(1)              // gates2 belong to step s-1
            STEP_ACT1_FIN(1)
            CX_COMPUTE(cxB0, cxB1, xvn)            // off-chain, for body B
        }
        __syncthreads();
        // ---------- body B: s = 2*s2+1 (read zz[1], write zz[0]) ----------
        {
            const int snx = (2 * s2 + 2 < T_LEN) ? (2 * s2 + 2) : (T_LEN - 1);
            const f4 xvn = *(const f4*)(xq + snx * IN_F);           // x(s+2)
            STEP_MFMA(1, cxB0, cxB1)
            STEP_REDIST()
            STEP_ACT2(0)                           // s >= 1 always here
            STEP_ACT1_FIN(0)
            CX_COMPUTE(cxA0, cxA1, xvn)            // off-chain, for next body A
        }
        __syncthreads();
    }

    // ================= epilogue: layer2 step T-1 (zz[0]: h1(511), h2(510)) ====
    {
        const s8b z0 = *(const s8b*)(&zz[0][0] + 0 * 512 + offF);
        const s8b z1 = *(const s8b*)(&zz[0][0] + 1 * 512 + offF);
        const s8b z3 = *(const s8b*)(&zz[0][0] + 3 * 512 + offF);
        f4 ac2;
        ac2 = MF(wf2[0].v, z0, bb2.v);
        ac2 = MF(wf2[1].v, z1, ac2);
        ac2 = MF(wf2[2].v, z3, ac2);
        const float dI = 1.0f + EX2(-ac2[0]);
        const float dF = 1.0f + EX2(-ac2[1]);
        const float rIF = rcp_(dI * dF);
        const float I = dF * rIF, F = dI * rIF;
        const float dG = EX2(ac2[2]) + 1.0f;
        const float dO = 1.0f + EX2(-ac2[3]);
        const float rGO = rcp_(dG * dO);
        const float Gg = 1.0f - 2.0f * (dO * rGO), O = dG * rGO;
        c2 = fmaf(F, c2, I * Gg);
        if (col < MB) h2f[col * H2 + u2] = O * tanh_(c2);
    }
    __syncthreads();

    // ================= FC head =================
    if (t < MB * FCN) {
        const int b = t >> 4, j = t & 15;
        float s1 = fc1_b[j];
        #pragma unroll
        for (int k = 0; k < H2; ++k)
            s1 = fmaf(fc1_w[j * H2 + k], h2f[b * H2 + k], s1);
        fcs[b * FCN + j] = fmaxf(s1, 0.f);
    }
    __syncthreads();
    if (t < MB) {
        float s2v = fc2_b[0];
        #pragma unroll
        for (int j = 0; j < FCN; ++j)
            s2v = fmaf(fc2_w[j], fcs[t * FCN + j], s2v);
        out[b0 + t] = s2v;
    }
}

extern "C" void kernel_launch(void* const* d_in, const int* in_sizes, int n_in,
                              void* d_out, int out_size, void* d_ws, size_t ws_size,
                              hipStream_t stream) {
    const float* x     = (const float*)d_in[0];
    const float* Wih1  = (const float*)d_in[1];
    const float* Whh1  = (const float*)d_in[2];
    const float* bih1  = (const float*)d_in[3];
    const float* bhh1  = (const float*)d_in[4];
    const float* Wih2  = (const float*)d_in[5];
    const float* Whh2  = (const float*)d_in[6];
    const float* bih2  = (const float*)d_in[7];
    const float* bhh2  = (const float*)d_in[8];
    const float* fc1_w = (const float*)d_in[9];
    const float* fc1_b = (const float*)d_in[10];
    const float* fc2_w = (const float*)d_in[11];
    const float* fc2_b = (const float*)d_in[12];
    float* out = (float*)d_out;

    const int n_batch = 2048;
    dim3 grid(n_batch / MB), block(BLK);
    lstm_mfma<<<grid, block, 0, stream>>>(x, Wih1, Whh1, bih1, bhh1,
                                          Wih2, Whh2, bih2, bhh2,
                                          fc1_w, fc1_b, fc2_w, fc2_b, out);
}

// Round 4
// 307.896 us; speedup vs baseline: 1.3197x; 1.3197x over previous
//
#include <hip/hip_runtime.h>

// LSTMTrafficPredictor: fused 2-layer LSTM + FC head via MFMA.
// B=2048, T=512, IN=4, H1=64, H2=32, FC=16, OUT=1.
//
// R21: wave-specialized layer split on the R19 champion (355.9us dispatch).
// R19/R20 post-mortems: R19 removed 130cy/SIMD VALU issue -> flat; R20 added
// ~400cy -> +110cy step. The step sits at the issue/latency balance point:
// the critical wave's OWN instruction stream co-limits with the dependency
// chain. Layer-2 work (3 MFMA + 8 trans + c2 math) lives on the layer-1
// critical wave in R19 but is already pipelined one step behind -> move it
// to dedicated waves.
// R21 structure: BLK=768 (12 waves). Waves 0-7: pure L1 recurrence
// (6 MFMA, ds_swizzle redistribution [mechanism verified R20], ACT1, h1+x
// stores). Waves 8-11: all of L2 (2 tiles/wave, 6 MFMA, 1 ACT2 job/lane =
// full lane utilization vs half before; total ACT2 trans issue halves).
// Same 1 barrier/body protocol; h1/h2 hand off through zz ping-pong exactly
// as before (L2 lags one step; epilogue computes h2(T-1)).
// CLOSED AXES (measured): issue-trimming on the balanced stream (R19 flat),
// VALU x-fold / CX_COMPUTE (R20 +23us), gsc vs swizzle (conflicts unchanged
// 28672 -> zz pattern, not gsc), multi-block/CU (spill), MB=16 (half CUs).
// k-map (K=128): [h1(0..63) | x(64..67) | 0(68..95) | h2(96..127)]
//   L1: 2 tiles/wave w<8 (unit w*8+nt*4+quad), ks {0,1,2}, C-init=bb1 (AGPR)
//   L2: 2 tiles/wave w>=8 (unit (w-8)*8+tt*4+quad), ks {0,1,3}, C-init=bb2
//   z offset(k,n) = (k>>5)*512 + (((k>>3)&3)*16+n)*8 + (k&7); frag read = lane*8.
// ACT job map (both layers): lane(quad,col) -> unit base + (col>>3)*4 + quad,
//   batch col&7; col<8 uses own acc tile 0, col>=8 uses swizzle(xor8) tile 1.

#define T_LEN 512
#define IN_F  4
#define H1    64
#define H2    32
#define FCN   16
#define MB    8
#define BLK   768
#define NW1   8     // layer-1 waves; waves NW1..11 are layer-2

typedef __attribute__((ext_vector_type(8))) short s8b;  // 8 bf16 = 4 VGPR
typedef __attribute__((ext_vector_type(4))) float f4;   // MFMA acc
typedef __attribute__((ext_vector_type(4))) int   i4;   // 4 dwords (pin unit)

union S8U { s8b v; i4 d; unsigned short u[8]; };
union F4U { f4 v; i4 d; float f[4]; };

// Pin 4 consecutive regs into AGPRs; asm def kills rematerialization.
#define APIN4(x) asm volatile("" : "+a"((x).d))

#define MF(a, b, c) __builtin_amdgcn_mfma_f32_16x16x32_bf16((a), (b), (c), 0, 0, 0)
#define EX2(x) __builtin_amdgcn_exp2f(x)

#define L2E   1.4426950408889634f
#define L2E2  2.885390081777927f   // 2*log2(e)

__device__ __forceinline__ float rcp_(float x) { return __builtin_amdgcn_rcpf(x); }
// tanh(x) via exp2: 1 - 2/(2^(2x*log2e)+1)
__device__ __forceinline__ float tanh_(float x) {
    return 1.0f - 2.0f * rcp_(EX2(x * L2E2) + 1.0f);
}

__device__ __forceinline__ unsigned short bf16_rne(float f) {   // loader only
    unsigned u = __float_as_uint(f);
    u = u + 0x7FFFu + ((u >> 16) & 1u);
    return (unsigned short)(u >> 16);
}
__device__ __forceinline__ unsigned short bf16_cvt(float f) {   // hot path: 1 instr
    unsigned r;
    asm("v_cvt_pk_bf16_f32 %0, %1, %2" : "=v"(r) : "v"(f), "v"(f));
    return (unsigned short)r;
}

// xor-8 lane swizzle of an f4 (4x ds_swizzle_b32, BitMode xor=8)
#define SWZ8(dst, src)                                                          \
    { F4U t_; t_.v = (src);                                                     \
      (dst).d[0] = __builtin_amdgcn_ds_swizzle(t_.d[0], 0x201F);                \
      (dst).d[1] = __builtin_amdgcn_ds_swizzle(t_.d[1], 0x201F);                \
      (dst).d[2] = __builtin_amdgcn_ds_swizzle(t_.d[2], 0x201F);                \
      (dst).d[3] = __builtin_amdgcn_ds_swizzle(t_.d[3], 0x201F); }

// Shared gate math (gates pre-scaled: i,f,o by log2e; g by 2*log2e).
#define GATES_MATH(G_, CREG, HOUT)                                              \
    const float dI = 1.0f + EX2(-(G_)[0]);                                      \
    const float dF = 1.0f + EX2(-(G_)[1]);                                      \
    const float rIF = rcp_(dI * dF);                                            \
    const float I = dF * rIF, F = dI * rIF;                                     \
    const float dG = EX2((G_)[2]) + 1.0f;                                       \
    const float dO = 1.0f + EX2(-(G_)[3]);                                      \
    const float rGO = rcp_(dG * dO);                                            \
    const float Gg = 1.0f - 2.0f * (dO * rGO), O = dG * rGO;                    \
    CREG = fmaf(F, CREG, I * Gg);                                               \
    const float HOUT = O * tanh_(CREG);

// ---- layer-1 body (waves 0..7): 6 MFMA, swizzle redist, ACT1, h1+x store --
#define L1_BODY(P, NP, LDOK)                                                    \
    {                                                                           \
        float xn = 0.f;                                                         \
        const bool ld_ = (t < MB * IN_F) && (LDOK);                             \
        if (ld_) xn = *xp;                                                      \
        const s8b z0 = *(const s8b*)(&zz[P][0] + 0 * 512 + offF);               \
        const s8b z1 = *(const s8b*)(&zz[P][0] + 1 * 512 + offF);               \
        const s8b z2 = *(const s8b*)(&zz[P][0] + 2 * 512 + offF);               \
        f4 a0 = MF(wf1[0][0].v, z0, bb1[0].v);                                  \
        f4 a1 = MF(wf1[1][0].v, z0, bb1[1].v);                                  \
        a0 = MF(wf1[0][1].v, z1, a0);                                           \
        a1 = MF(wf1[1][1].v, z1, a1);                                           \
        a0 = MF(wf1[0][2].v, z2, a0);                                           \
        a1 = MF(wf1[1][2].v, z2, a1);                                           \
        F4U rsw; SWZ8(rsw, a1)                                                  \
        f4 g_;                                                                  \
        _Pragma("unroll")                                                       \
        for (int j_ = 0; j_ < 4; ++j_) g_[j_] = lowc ? a0[j_] : rsw.f[j_];      \
        GATES_MATH(g_, c1, h_)                                                  \
        zz[NP][offH] = bf16_cvt(h_);                                            \
        if (ld_) zz[NP][1024 + xn_ * 8 + xf_] = bf16_cvt(xn);                   \
        xp += IN_F;                                                             \
    }

// ---- layer-2 body (waves 8..11): 6 MFMA, swizzle redist, ACT2, h2 store ---
// Computes gates2 for the LAGGED step (inputs h1(s-1), h2(s-2) from zz[P]).
#define L2_MFMA(P)                                                              \
    f4 q0, q1;                                                                  \
    {                                                                           \
        const s8b z0 = *(const s8b*)(&zz[P][0] + 0 * 512 + offF);               \
        const s8b z1 = *(const s8b*)(&zz[P][0] + 1 * 512 + offF);               \
        const s8b z3 = *(const s8b*)(&zz[P][0] + 3 * 512 + offF);               \
        q0 = MF(wf2[0][0].v, z0, bb2[0].v);                                     \
        q1 = MF(wf2[1][0].v, z0, bb2[1].v);                                     \
        q0 = MF(wf2[0][1].v, z1, q0);                                           \
        q1 = MF(wf2[1][1].v, z1, q1);                                           \
        q0 = MF(wf2[0][2].v, z3, q0);                                           \
        q1 = MF(wf2[1][2].v, z3, q1);                                           \
    }

#define L2_ACT(NP)                                                              \
    {                                                                           \
        F4U rsw; SWZ8(rsw, q1)                                                  \
        f4 g_;                                                                  \
        _Pragma("unroll")                                                       \
        for (int j_ = 0; j_ < 4; ++j_) g_[j_] = lowc ? q0[j_] : rsw.f[j_];      \
        GATES_MATH(g_, c2, h_)                                                  \
        zz[NP][off2j] = bf16_cvt(h_);                                           \
    }

__global__ __launch_bounds__(BLK, 3)
void lstm_mfma(const float* __restrict__ x,
               const float* __restrict__ Wih1, const float* __restrict__ Whh1,
               const float* __restrict__ bih1, const float* __restrict__ bhh1,
               const float* __restrict__ Wih2, const float* __restrict__ Whh2,
               const float* __restrict__ bih2, const float* __restrict__ bhh2,
               const float* __restrict__ fc1_w, const float* __restrict__ fc1_b,
               const float* __restrict__ fc2_w, const float* __restrict__ fc2_b,
               float* __restrict__ out)
{
    __shared__ __align__(16) unsigned short zz[2][2048];     // 8 KB
    __shared__ __align__(16) float h2f[MB * H2];
    __shared__ __align__(16) float fcs[MB * FCN];

    const int t    = threadIdx.x;
    const int lane = t & 63;
    const int w    = t >> 6;      // wave 0..11
    const int col  = lane & 15;
    const int quad = lane >> 4;
    const int b0   = blockIdx.x * MB;
    const bool lowc = (col < 8);
    const int w2   = (w >= NW1) ? (w - NW1) : 0;   // L2 wave idx (clamped)

    // ---- weight fragments (bf16, exp2-folded: g-gate rows x 2*log2e) ----
    const float wsc = ((col & 3) == 2) ? L2E2 : L2E;
    S8U wf1[2][3];                // layer1: 2 tiles x ks {0,1,2}
    S8U wf2[2][3];                // layer2: 2 tiles x ks {0,1,3}
    #pragma unroll
    for (int nt = 0; nt < 2; ++nt) {
        const int r1 = (col & 3) * 64 + w2 * 8 + nt * 4 + (col >> 2);  // dummy ok for L2 waves
        const int r1u = (col & 3) * 64 + (w < NW1 ? w : 0) * 8 + nt * 4 + (col >> 2);
        (void)r1;
        #pragma unroll
        for (int ks = 0; ks < 3; ++ks) {
            #pragma unroll
            for (int j = 0; j < 8; ++j) {
                const int k = ks * 32 + quad * 8 + j;
                float wv = 0.f;
                if      (k < H1)           wv = Whh1[r1u * H1 + k];
                else if (k < H1 + IN_F)    wv = Wih1[r1u * IN_F + (k - H1)];
                wf1[nt][ks].u[j] = bf16_rne(wv * wsc);
            }
        }
    }
    #pragma unroll
    for (int tt = 0; tt < 2; ++tt) {
        const int r2 = (col & 3) * 32 + w2 * 8 + tt * 4 + (col >> 2);
        #pragma unroll
        for (int kf = 0; kf < 3; ++kf) {
            #pragma unroll
            for (int j = 0; j < 8; ++j) {
                const int k = ((kf < 2) ? kf * 32 : 96) + quad * 8 + j;
                const float wv = (k < H1) ? Wih2[r2 * H1 + k]
                                          : Whh2[r2 * H2 + (k - 96)];
                wf2[tt][kf].u[j] = bf16_rne(wv * wsc);
            }
        }
    }
    // biases as exact-f32 MFMA C-init (pre-scaled)
    F4U bb1[2], bb2[2];
    #pragma unroll
    for (int j = 0; j < 4; ++j) {
        const float bsc = (j == 2) ? L2E2 : L2E;
        const int u1a = (w < NW1 ? w : 0) * 8 + quad;         // nt=0 unit
        const int u1b = u1a + 4;                              // nt=1 unit
        bb1[0].f[j] = (bih1[j * 64 + u1a] + bhh1[j * 64 + u1a]) * bsc;
        bb1[1].f[j] = (bih1[j * 64 + u1b] + bhh1[j * 64 + u1b]) * bsc;
        const int u2a = w2 * 8 + quad;                        // tt=0 unit
        const int u2b = u2a + 4;                              // tt=1 unit
        bb2[0].f[j] = (bih2[j * 32 + u2a] + bhh2[j * 32 + u2a]) * bsc;
        bb2[1].f[j] = (bih2[j * 32 + u2b] + bhh2[j * 32 + u2b]) * bsc;
    }

    // ---- PIN fragments + biases into AGPRs ----
    #pragma unroll
    for (int nt = 0; nt < 2; ++nt)
        #pragma unroll
        for (int ks = 0; ks < 3; ++ks) { APIN4(wf1[nt][ks]); APIN4(wf2[nt][ks]); }
    APIN4(bb1[0]); APIN4(bb1[1]); APIN4(bb2[0]); APIN4(bb2[1]);

    // ---- init LDS: zero z (both buffers) ----
    {
        int* pz = (int*)zz;       // 2*2048 shorts = 2048 ints
        for (int i = t; i < 2048; i += BLK) pz[i] = 0;
    }
    __syncthreads();
    if (t < MB * IN_F) {                    // x(0) at k=64+f: off = 1024 + n*8 + f
        const int n = t >> 2, f = t & 3;
        const float xv = x[(size_t)(b0 + n) * T_LEN * IN_F + f];
        zz[0][1024 + n * 8 + f] = bf16_rne(xv);
    }
    float c1 = 0.f;   // L1 job: unit w*8+(col>>3)*4+quad, batch col&7
    float c2 = 0.f;   // L2 job: unit w2*8+(col>>3)*4+quad, batch col&7

    // store offsets
    const int uH    = w * 8 + ((col >> 3) << 2) + quad;            // L1 (w<8)
    const int nH    = col & 7;
    const int offH  = (uH >> 5) * 512 + (((uH >> 3) & 3) * 16 + nH) * 8 + (uH & 7);
    const int u2j   = w2 * 8 + ((col >> 3) << 2) + quad;           // L2 (w>=8)
    const int off2j = 1536 + (((u2j >> 3) & 3) * 16 + nH) * 8 + (u2j & 7);
    const int offF  = lane * 8;                    // frag read base
    const int xn_   = (t >> 2) & 7, xf_ = t & 3;   // x-prefetch role (t < 32)
    const float* xp = x + (size_t)(b0 + xn_) * T_LEN * IN_F + IN_F + xf_;  // -> x(1)
    __syncthreads();

    // ================= main recurrence: unrolled x2, 1 barrier/body ==========
    #pragma unroll 1
    for (int s2 = 0; s2 < T_LEN / 2; ++s2) {
        // ---------- body A: s = 2*s2 (read zz[0], write zz[1]) ----------
        if (w < NW1) {
            L1_BODY(0, 1, 1)
        } else {
            L2_MFMA(0)
            if (s2 != 0) L2_ACT(1)       // first body: h2(-1) must stay 0
        }
        __syncthreads();
        // ---------- body B: s = 2*s2+1 (read zz[1], write zz[0]) ----------
        if (w < NW1) {
            L1_BODY(1, 0, (s2 != T_LEN / 2 - 1))
        } else {
            L2_MFMA(1)
            L2_ACT(0)
        }
        __syncthreads();
    }

    // ================= epilogue: layer2 step T-1 (zz[0]: h1(511), h2(510)) ====
    if (w >= NW1) {
        L2_MFMA(0)
        {
            F4U rsw; SWZ8(rsw, q1)
            f4 g_;
            #pragma unroll
            for (int j_ = 0; j_ < 4; ++j_) g_[j_] = lowc ? q0[j_] : rsw.f[j_];
            GATES_MATH(g_, c2, h_)
            h2f[nH * H2 + u2j] = h_;
        }
    }
    __syncthreads();

    // ================= FC head =================
    if (t < MB * FCN) {
        const int b = t >> 4, j = t & 15;
        float s1 = fc1_b[j];
        #pragma unroll
        for (int k = 0; k < H2; ++k)
            s1 = fmaf(fc1_w[j * H2 + k], h2f[b * H2 + k], s1);
        fcs[b * FCN + j] = fmaxf(s1, 0.f);
    }
    __syncthreads();
    if (t < MB) {
        float s2v = fc2_b[0];
        #pragma unroll
        for (int j = 0; j < FCN; ++j)
            s2v = fmaf(fc2_w[j], fcs[t * FCN + j], s2v);
        out[b0 + t] = s2v;
    }
}

extern "C" void kernel_launch(void* const* d_in, const int* in_sizes, int n_in,
                              void* d_out, int out_size, void* d_ws, size_t ws_size,
                              hipStream_t stream) {
    const float* x     = (const float*)d_in[0];
    const float* Wih1  = (const float*)d_in[1];
    const float* Whh1  = (const float*)d_in[2];
    const float* bih1  = (const float*)d_in[3];
    const float* bhh1  = (const float*)d_in[4];
    const float* Wih2  = (const float*)d_in[5];
    const float* Whh2  = (const float*)d_in[6];
    const float* bih2  = (const float*)d_in[7];
    const float* bhh2  = (const float*)d_in[8];
    const float* fc1_w = (const float*)d_in[9];
    const float* fc1_b = (const float*)d_in[10];
    const float* fc2_w = (const float*)d_in[11];
    const float* fc2_b = (const float*)d_in[12];
    float* out = (float*)d_out;

    const int n_batch = 2048;
    dim3 grid(n_batch / MB), block(BLK);
    lstm_mfma<<<grid, block, 0, stream>>>(x, Wih1, Whh1, bih1, bhh1,
                                          Wih2, Whh2, bih2, bhh2,
                                          fc1_w, fc1_b, fc2_w, fc2_b, out);
}